// Round 1
// baseline (452.464 us; speedup 1.0000x reference)
//
#include <hip/hip_runtime.h>
#include <hip/hip_bf16.h>

#define N_SRC 65536
#define N_DST 16384
#define NEDGE 262144
#define FIN 256
#define HID 128
#define NH 4
#define NPOI 100000
#define KNB 50
#define NEG 0.2f

typedef short bf8 __attribute__((ext_vector_type(8)));
typedef float f32x4 __attribute__((ext_vector_type(4)));

static __device__ __forceinline__ short f2bf(float f) {
    union { float f; unsigned u; } v; v.f = f;
    unsigned r = v.u + 0x7fffu + ((v.u >> 16) & 1u);
    return (short)(r >> 16);
}
static __device__ __forceinline__ float bf2f(short b) {
    union { unsigned u; float f; } v; v.u = ((unsigned)(unsigned short)b) << 16;
    return v.f;
}

// ---- float -> bf16 convert (vec4) ----
__global__ void k_f2bf(const float* __restrict__ in, short* __restrict__ out, int n4) {
    int i = blockIdx.x * blockDim.x + threadIdx.x;
    if (i >= n4) return;
    float4 v = ((const float4*)in)[i];
    short4 o; o.x = f2bf(v.x); o.y = f2bf(v.y); o.z = f2bf(v.z); o.w = f2bf(v.w);
    ((short4*)out)[i] = o;
}

// ---- gather poi_cat_feat[output_nodes] -> bf16 [N_DST,256] ----
__global__ void k_gather_cf(const float* __restrict__ poi, const int* __restrict__ nodes,
                            short* __restrict__ cf) {
    int i = blockIdx.x * blockDim.x + threadIdx.x;   // < N_DST*64
    int row = i >> 6, c4 = i & 63;
    int nid = nodes[row];
    float4 v = ((const float4*)(poi + (size_t)nid * FIN))[c4];
    short4 o; o.x = f2bf(v.x); o.y = f2bf(v.y); o.z = f2bf(v.z); o.w = f2bf(v.w);
    ((short4*)(cf + (size_t)row * FIN))[c4] = o;
}

// ---- CSR build ----
__global__ void k_hist(const int* __restrict__ dst, int* __restrict__ counts) {
    int e = blockIdx.x * blockDim.x + threadIdx.x;
    if (e < NEDGE) atomicAdd(&counts[dst[e]], 1);
}

__global__ void k_scan(const int* __restrict__ counts, int* __restrict__ offsets,
                       int* __restrict__ cursor) {
    __shared__ int part[1024];
    int t = threadIdx.x;
    int base = t * 16;
    int loc[16]; int s = 0;
    for (int i = 0; i < 16; i++) { loc[i] = counts[base + i]; s += loc[i]; }
    part[t] = s; __syncthreads();
    for (int off = 1; off < 1024; off <<= 1) {
        int v = (t >= off) ? part[t - off] : 0;
        __syncthreads();
        part[t] += v;
        __syncthreads();
    }
    int run = (t == 0) ? 0 : part[t - 1];
    for (int i = 0; i < 16; i++) { offsets[base + i] = run; cursor[base + i] = run; run += loc[i]; }
    if (t == 1023) offsets[N_DST] = run;
}

__global__ void k_scatter(const int* __restrict__ dst, int* __restrict__ cursor,
                          int* __restrict__ edge_ids) {
    int e = blockIdx.x * blockDim.x + threadIdx.x;
    if (e < NEDGE) {
        int d = dst[e];
        int pos = atomicAdd(&cursor[d], 1);
        edge_ids[pos] = e;
    }
}

// ---- bf16 MFMA GEMM: C[M,N] = A[M,256] @ W[N,256]^T, optional per-row scale ----
// block = 256 thr (4 waves). Block tile 256 rows x 64 cols; wave w: rows [.. +64).
__global__ __launch_bounds__(256) void k_gemm(const short* __restrict__ A,
                                              const short* __restrict__ W,
                                              short* __restrict__ C,
                                              const float* __restrict__ scale, int N) {
    int wv = threadIdx.x >> 6;
    int lane = threadIdx.x & 63;
    int l15 = lane & 15, quad = lane >> 4;
    int colBase = blockIdx.x * 64;
    int rowBase = blockIdx.y * 256 + wv * 64;
    const short* Ab = A + (size_t)(rowBase + l15) * FIN + quad * 8;
    const short* Wb = W + (size_t)(colBase + l15) * FIN + quad * 8;
    f32x4 acc[4][4] = {};
    for (int k0 = 0; k0 < FIN; k0 += 32) {
        bf8 a[4], b[4];
#pragma unroll
        for (int i = 0; i < 4; i++) a[i] = *(const bf8*)(Ab + (size_t)i * 16 * FIN + k0);
#pragma unroll
        for (int j = 0; j < 4; j++) b[j] = *(const bf8*)(Wb + (size_t)j * 16 * FIN + k0);
#pragma unroll
        for (int i = 0; i < 4; i++)
#pragma unroll
            for (int j = 0; j < 4; j++)
                acc[i][j] = __builtin_amdgcn_mfma_f32_16x16x32_bf16(a[i], b[j], acc[i][j], 0, 0, 0);
    }
#pragma unroll
    for (int i = 0; i < 4; i++) {
#pragma unroll
        for (int r = 0; r < 4; r++) {
            int row = rowBase + i * 16 + quad * 4 + r;
            float sc = scale ? scale[row] : 1.0f;
#pragma unroll
            for (int j = 0; j < 4; j++) {
                int col = colBase + j * 16 + l15;
                C[(size_t)row * N + col] = f2bf(acc[i][j][r] * sc);
            }
        }
    }
}

// ---- el/er: per-node attn dots from bf16 feat_src ----
__global__ __launch_bounds__(256) void k_elr(const short* __restrict__ feat_src,
                                             const float* __restrict__ attn_l,
                                             const float* __restrict__ attn_r,
                                             float* __restrict__ el, float* __restrict__ er) {
    int wv = threadIdx.x >> 6, lane = threadIdx.x & 63;
    int n = blockIdx.x * 4 + wv;
    int h = lane >> 4;
    int seg = lane & 15;
    bf8 v = *(const bf8*)(feat_src + (size_t)n * (NH * HID) + h * HID + seg * 8);
    const float* al = attn_l + h * HID + seg * 8;
    const float* ar = attn_r + h * HID + seg * 8;
    float sl = 0.f, sr = 0.f;
#pragma unroll
    for (int j = 0; j < 8; j++) {
        float f = bf2f(v[j]);
        sl += f * al[j];
        sr += f * ar[j];
    }
    for (int m = 1; m < 16; m <<= 1) { sl += __shfl_xor(sl, m); sr += __shfl_xor(sr, m); }
    if (seg == 0) {
        el[n * NH + h] = sl;
        if (n < N_DST) er[n * NH + h] = sr;
    }
}

// ---- s[i] = sum of first count coeffs ----
__global__ __launch_bounds__(256) void k_s(const float* __restrict__ poi_coeff,
                                           const int* __restrict__ out_nodes,
                                           const int* __restrict__ ncounts,
                                           float* __restrict__ s) {
    int wv = threadIdx.x >> 6, lane = threadIdx.x & 63;
    int i = blockIdx.x * 4 + wv;
    int nid = out_nodes[i];
    int cnt = ncounts[nid];
    float v = (lane < cnt && lane < KNB) ? poi_coeff[(size_t)nid * KNB + lane] : 0.f;
    for (int m = 1; m < 64; m <<= 1) v += __shfl_xor(v, m);
    if (lane == 0) s[i] = v;
}

// ---- fused per-dst softmax + aggregation + epilogue ----
__global__ __launch_bounds__(256) void k_agg(const int* __restrict__ offsets,
                                             const int* __restrict__ edge_ids,
                                             const int* __restrict__ src_idx,
                                             const float* __restrict__ el,
                                             const float* __restrict__ er,
                                             const short* __restrict__ feat_src,
                                             const short* __restrict__ res,
                                             const float* __restrict__ bias,
                                             const short* __restrict__ fdist,
                                             float* __restrict__ out) {
    __shared__ float red[256][4];
    __shared__ float a_sh[64][4];
    __shared__ int src_sh[64];
    __shared__ float m_sh[4], inv_sh[4];
    int d = blockIdx.x;
    int t = threadIdx.x;
    int start = offsets[d], end = offsets[d + 1];
    int cnt = end - start;
    float er4[4];
    er4[0] = er[d * 4 + 0]; er4[1] = er[d * 4 + 1];
    er4[2] = er[d * 4 + 2]; er4[3] = er[d * 4 + 3];

    // pass A: per-head max
    float mx[4] = {-1e30f, -1e30f, -1e30f, -1e30f};
    for (int i = t; i < cnt; i += 256) {
        int e = edge_ids[start + i];
        int sIdx = src_idx[e];
        float4 elv = *(const float4*)(el + (size_t)sIdx * 4);
        float v0 = elv.x + er4[0]; v0 = v0 > 0 ? v0 : NEG * v0;
        float v1 = elv.y + er4[1]; v1 = v1 > 0 ? v1 : NEG * v1;
        float v2 = elv.z + er4[2]; v2 = v2 > 0 ? v2 : NEG * v2;
        float v3 = elv.w + er4[3]; v3 = v3 > 0 ? v3 : NEG * v3;
        mx[0] = fmaxf(mx[0], v0); mx[1] = fmaxf(mx[1], v1);
        mx[2] = fmaxf(mx[2], v2); mx[3] = fmaxf(mx[3], v3);
    }
    for (int h = 0; h < 4; h++) red[t][h] = mx[h];
    __syncthreads();
    for (int off = 128; off >= 1; off >>= 1) {
        if (t < off)
            for (int h = 0; h < 4; h++) red[t][h] = fmaxf(red[t][h], red[t + off][h]);
        __syncthreads();
    }
    if (t < 4) m_sh[t] = (cnt > 0) ? red[0][t] : 0.f;
    __syncthreads();
    float m4[4] = {m_sh[0], m_sh[1], m_sh[2], m_sh[3]};

    // pass B: denom
    float sm[4] = {0.f, 0.f, 0.f, 0.f};
    for (int i = t; i < cnt; i += 256) {
        int e = edge_ids[start + i];
        int sIdx = src_idx[e];
        float4 elv = *(const float4*)(el + (size_t)sIdx * 4);
        float v0 = elv.x + er4[0]; v0 = v0 > 0 ? v0 : NEG * v0;
        float v1 = elv.y + er4[1]; v1 = v1 > 0 ? v1 : NEG * v1;
        float v2 = elv.z + er4[2]; v2 = v2 > 0 ? v2 : NEG * v2;
        float v3 = elv.w + er4[3]; v3 = v3 > 0 ? v3 : NEG * v3;
        sm[0] += __expf(v0 - m4[0]); sm[1] += __expf(v1 - m4[1]);
        sm[2] += __expf(v2 - m4[2]); sm[3] += __expf(v3 - m4[3]);
    }
    __syncthreads();
    for (int h = 0; h < 4; h++) red[t][h] = sm[h];
    __syncthreads();
    for (int off = 128; off >= 1; off >>= 1) {
        if (t < off)
            for (int h = 0; h < 4; h++) red[t][h] += red[t + off][h];
        __syncthreads();
    }
    if (t < 4) inv_sh[t] = 1.f / fmaxf(red[0][t], 1e-9f);
    __syncthreads();

    // pass C: weighted gather-sum. thread owns cols 2t, 2t+1
    int c0 = 2 * t;
    int h = c0 >> 7;
    float acc0 = 0.f, acc1 = 0.f;
    for (int base = 0; base < cnt; base += 64) {
        int nc = min(64, cnt - base);
        __syncthreads();
        if (t < nc * 4) {
            int ei = t >> 2, hh = t & 3;
            int e = edge_ids[start + base + ei];
            int sIdx = src_idx[e];
            if (hh == 0) src_sh[ei] = sIdx;
            float v = el[sIdx * 4 + hh] + er4[hh];
            v = v > 0 ? v : NEG * v;
            a_sh[ei][hh] = __expf(v - m_sh[hh]) * inv_sh[hh];
        }
        __syncthreads();
        for (int c = 0; c < nc; c++) {
            int srow = src_sh[c];
            float af = a_sh[c][h];
            unsigned pk = *(const unsigned*)(feat_src + (size_t)srow * 512 + c0);
            acc0 += af * bf2f((short)(pk & 0xffff));
            acc1 += af * bf2f((short)(pk >> 16));
        }
    }

    // epilogue
    unsigned rp = *(const unsigned*)(res + (size_t)d * 512 + c0);
    float r0 = bf2f((short)(rp & 0xffff)), r1 = bf2f((short)(rp >> 16));
    float b0 = bias[c0], b1 = bias[c0 + 1];
    unsigned fp = *(const unsigned*)(fdist + (size_t)d * HID + (c0 & 127));
    float f0 = bf2f((short)(fp & 0xffff)), f1 = bf2f((short)(fp >> 16));
    float g0 = acc0 + r0 + b0; g0 = g0 > 0 ? g0 : expm1f(g0);
    float g1 = acc1 + r1 + b1; g1 = g1 > 0 ? g1 : expm1f(g1);
    float o0 = (g0 + f0) * 0.5f; o0 = o0 > 0 ? o0 : 0.f;
    float o1 = (g1 + f1) * 0.5f; o1 = o1 > 0 ? o1 : 0.f;
    ((float2*)(out + (size_t)d * 512))[t] = make_float2(o0, o1);
}

extern "C" void kernel_launch(void* const* d_in, const int* in_sizes, int n_in,
                              void* d_out, int out_size, void* d_ws, size_t ws_size,
                              hipStream_t stream) {
    const float* feat      = (const float*)d_in[0];
    const float* poi_cat   = (const float*)d_in[1];
    const float* poi_coeff = (const float*)d_in[2];
    const float* fc_w      = (const float*)d_in[3];
    const float* attn_l    = (const float*)d_in[4];
    const float* attn_r    = (const float*)d_in[5];
    const float* bias_p    = (const float*)d_in[6];
    const float* res_w     = (const float*)d_in[7];
    const float* w_w       = (const float*)d_in[8];
    const int* src_idx     = (const int*)d_in[9];
    const int* dst_idx     = (const int*)d_in[10];
    const int* out_nodes   = (const int*)d_in[11];
    const int* ncounts     = (const int*)d_in[12];
    float* out = (float*)d_out;

    char* w = (char*)d_ws;
    auto alloc = [&](size_t bytes) -> char* {
        char* p = w; w += (bytes + 255) & ~(size_t)255; return p;
    };
    short* feat_bf  = (short*)alloc((size_t)N_SRC * FIN * 2);
    short* fcw_bf   = (short*)alloc((size_t)512 * FIN * 2);
    short* resw_bf  = (short*)alloc((size_t)512 * FIN * 2);
    short* ww_bf    = (short*)alloc((size_t)HID * FIN * 2);
    short* cf_bf    = (short*)alloc((size_t)N_DST * FIN * 2);
    short* feat_src = (short*)alloc((size_t)N_SRC * 512 * 2);
    short* res      = (short*)alloc((size_t)N_DST * 512 * 2);
    short* fdist    = (short*)alloc((size_t)N_DST * HID * 2);
    float* el       = (float*)alloc((size_t)N_SRC * 4 * 4);
    float* er       = (float*)alloc((size_t)N_DST * 4 * 4);
    float* sArr     = (float*)alloc((size_t)N_DST * 4);
    int* counts     = (int*)alloc((size_t)N_DST * 4);
    int* offsets    = (int*)alloc((size_t)(N_DST + 1) * 4);
    int* cursor     = (int*)alloc((size_t)N_DST * 4);
    int* edge_ids   = (int*)alloc((size_t)NEDGE * 4);

    hipMemsetAsync(counts, 0, N_DST * 4, stream);

    k_f2bf<<<(N_SRC * FIN / 4 + 255) / 256, 256, 0, stream>>>(feat, feat_bf, N_SRC * FIN / 4);
    k_f2bf<<<(512 * FIN / 4 + 255) / 256, 256, 0, stream>>>(fc_w, fcw_bf, 512 * FIN / 4);
    k_f2bf<<<(512 * FIN / 4 + 255) / 256, 256, 0, stream>>>(res_w, resw_bf, 512 * FIN / 4);
    k_f2bf<<<(HID * FIN / 4 + 255) / 256, 256, 0, stream>>>(w_w, ww_bf, HID * FIN / 4);
    k_gather_cf<<<N_DST * 64 / 256, 256, 0, stream>>>(poi_cat, out_nodes, cf_bf);

    k_hist<<<NEDGE / 256, 256, 0, stream>>>(dst_idx, counts);
    k_scan<<<1, 1024, 0, stream>>>(counts, offsets, cursor);
    k_scatter<<<NEDGE / 256, 256, 0, stream>>>(dst_idx, cursor, edge_ids);

    k_gemm<<<dim3(8, N_SRC / 256), 256, 0, stream>>>(feat_bf, fcw_bf, feat_src, nullptr, 512);
    k_gemm<<<dim3(8, N_DST / 256), 256, 0, stream>>>(feat_bf, resw_bf, res, nullptr, 512);
    k_s<<<N_DST / 4, 256, 0, stream>>>(poi_coeff, out_nodes, ncounts, sArr);
    k_gemm<<<dim3(2, N_DST / 256), 256, 0, stream>>>(cf_bf, ww_bf, fdist, sArr, HID);

    k_elr<<<N_SRC / 4, 256, 0, stream>>>(feat_src, attn_l, attn_r, el, er);
    k_agg<<<N_DST, 256, 0, stream>>>(offsets, edge_ids, src_idx, el, er, feat_src,
                                     res, bias_p, fdist, out);
}

// Round 2
// 418.968 us; speedup vs baseline: 1.0799x; 1.0799x over previous
//
#include <hip/hip_runtime.h>

#define N_SRC 65536
#define N_DST 16384
#define NEDGE 262144
#define FIN 256
#define HID 128
#define KNB 50
#define NEG 0.2f

typedef short bf8 __attribute__((ext_vector_type(8)));
typedef float f32x4 __attribute__((ext_vector_type(4)));
typedef unsigned int u32;

static __device__ __forceinline__ short f2bf(float f) {
    union { float f; unsigned u; } v; v.f = f;
    unsigned r = v.u + 0x7fffu + ((v.u >> 16) & 1u);
    return (short)(r >> 16);
}
static __device__ __forceinline__ float bf2f(short b) {
    union { unsigned u; float f; } v; v.u = ((unsigned)(unsigned short)b) << 16;
    return v.f;
}

// ---- feat fp32 -> bf16 ----
__global__ void k_f2bf(const float* __restrict__ in, short* __restrict__ out, int n4) {
    int i = blockIdx.x * blockDim.x + threadIdx.x;
    if (i >= n4) return;
    float4 v = ((const float4*)in)[i];
    short4 o; o.x = f2bf(v.x); o.y = f2bf(v.y); o.z = f2bf(v.z); o.w = f2bf(v.w);
    ((short4*)out)[i] = o;
}

// ---- all three weight matrices -> bf16 in one launch ----
// fc_w: 512x256 (32768 float4), res_w: 512x256 (32768), w_w: 128x256 (8192). total 73728.
__global__ void k_prep_w(const float* __restrict__ fc, const float* __restrict__ rw,
                         const float* __restrict__ ww, short* __restrict__ fco,
                         short* __restrict__ rwo, short* __restrict__ wwo) {
    int i = blockIdx.x * 256 + threadIdx.x;
    const float* src; short* dst; int off;
    if (i < 32768) { src = fc; dst = fco; off = i; }
    else if (i < 65536) { src = rw; dst = rwo; off = i - 32768; }
    else { src = ww; dst = wwo; off = i - 65536; }
    float4 v = ((const float4*)src)[off];
    short4 o; o.x = f2bf(v.x); o.y = f2bf(v.y); o.z = f2bf(v.z); o.w = f2bf(v.w);
    ((short4*)dst)[off] = o;
}

// ---- gather poi_cat_feat[output_nodes] -> bf16 [N_DST,256] ----
__global__ void k_gather_cf(const float* __restrict__ poi, const int* __restrict__ nodes,
                            short* __restrict__ cf) {
    int i = blockIdx.x * blockDim.x + threadIdx.x;   // < N_DST*64
    int row = i >> 6, c4 = i & 63;
    int nid = nodes[row];
    float4 v = ((const float4*)(poi + (size_t)nid * FIN))[c4];
    short4 o; o.x = f2bf(v.x); o.y = f2bf(v.y); o.z = f2bf(v.z); o.w = f2bf(v.w);
    ((short4*)(cf + (size_t)row * FIN))[c4] = o;
}

// ---- CSR build ----
__global__ void k_hist(const int* __restrict__ dst, int* __restrict__ counts) {
    int e = blockIdx.x * blockDim.x + threadIdx.x;
    if (e < NEDGE) atomicAdd(&counts[dst[e]], 1);
}

__global__ void k_scan(const int* __restrict__ counts, int* __restrict__ offsets,
                       int* __restrict__ cursor) {
    __shared__ int part[1024];
    int t = threadIdx.x;
    int base = t * 16;
    int loc[16]; int s = 0;
    for (int i = 0; i < 16; i++) { loc[i] = counts[base + i]; s += loc[i]; }
    part[t] = s; __syncthreads();
    for (int off = 1; off < 1024; off <<= 1) {
        int v = (t >= off) ? part[t - off] : 0;
        __syncthreads();
        part[t] += v;
        __syncthreads();
    }
    int run = (t == 0) ? 0 : part[t - 1];
    for (int i = 0; i < 16; i++) { offsets[base + i] = run; cursor[base + i] = run; run += loc[i]; }
    if (t == 1023) offsets[N_DST] = run;
}

__global__ void k_scatter(const int* __restrict__ dst, int* __restrict__ cursor,
                          int* __restrict__ edge_ids) {
    int e = blockIdx.x * blockDim.x + threadIdx.x;
    if (e < NEDGE) {
        int d = dst[e];
        int pos = atomicAdd(&cursor[d], 1);
        edge_ids[pos] = e;
    }
}

// ---- bf16 MFMA GEMM: C[M,N] = A[M,256] @ W[N,256]^T ----
// Block: 64 rows x ALL N cols. Whole K (256) of the 64-row A tile staged once in
// LDS (32 KB) via global_load_lds(16B) with XOR swizzle (c ^= r&7) so the
// ds_read_b128 frag reads are conflict-free (row stride 512B would be 16-way).
// Wave w loops col-tiles {w, w+4, ...}. W frags come from global (L2-hot, 262KB).
// do_elr: fused el/er epilogue — read back the hot C tile, dot with attn in LDS.
__global__ __launch_bounds__(256) void k_gemm(
    const short* __restrict__ A, const short* __restrict__ W, short* __restrict__ C,
    const float* __restrict__ scale, int N, int ntiles, int do_elr,
    const float* __restrict__ attn_l, const float* __restrict__ attn_r,
    float* __restrict__ el, float* __restrict__ er, int ndst) {
    __shared__ __align__(16) char smem[32768];
    int t = threadIdx.x, wv = t >> 6, lane = t & 63;
    int l15 = lane & 15, quad = lane >> 4;
    int rowBase = blockIdx.x * 64;
    const short* tbase = A + (size_t)rowBase * FIN;
    // stage 32 KB: LDS granule L holds global granule (r*32 + ((L&31)^(r&7)))
#pragma unroll
    for (int q = 0; q < 8; q++) {
        int slab = wv * 8 + q;
        int L = slab * 64 + lane;
        int r = L >> 5, cl = L & 31;
        int cg = cl ^ (r & 7);
        __builtin_amdgcn_global_load_lds(
            (const __attribute__((address_space(1))) void*)(tbase + r * FIN + cg * 8),
            (__attribute__((address_space(3))) void*)(smem + slab * 1024), 16, 0, 0);
    }
    __syncthreads();
    int swz = l15 & 7;
    for (int jt = wv; jt < ntiles; jt += 4) {
        int colBase = jt * 64;
        const short* Wb = W + (size_t)(colBase + l15) * FIN + quad * 8;
        f32x4 acc[4][4] = {};
#pragma unroll
        for (int kk = 0; kk < 8; kk++) {
            bf8 a[4], b[4];
#pragma unroll
            for (int i = 0; i < 4; i++) {
                int off = (((i * 16 + l15) << 5) + ((quad + (kk << 2)) ^ swz)) << 4;
                a[i] = *(const bf8*)(smem + off);
            }
#pragma unroll
            for (int j = 0; j < 4; j++)
                b[j] = *(const bf8*)(Wb + (size_t)j * 16 * FIN + kk * 32);
#pragma unroll
            for (int i = 0; i < 4; i++)
#pragma unroll
                for (int j = 0; j < 4; j++)
                    acc[i][j] = __builtin_amdgcn_mfma_f32_16x16x32_bf16(a[i], b[j], acc[i][j], 0, 0, 0);
        }
#pragma unroll
        for (int i = 0; i < 4; i++)
#pragma unroll
            for (int r = 0; r < 4; r++) {
                int row = rowBase + i * 16 + quad * 4 + r;
                float sc = scale ? scale[row] : 1.0f;
#pragma unroll
                for (int j = 0; j < 4; j++)
                    C[(size_t)row * N + colBase + j * 16 + l15] = f2bf(acc[i][j][r] * sc);
            }
    }
    if (do_elr) {
        __syncthreads();   // drains C stores (vmcnt) + lets us reuse smem
        float* alds = (float*)smem;
        for (int i = t; i < 512; i += 256) { alds[i] = attn_l[i]; alds[512 + i] = attn_r[i]; }
        __syncthreads();
        int row = t >> 2, s = t & 3;   // s == head (128 cols each)
        const short* crow = C + (size_t)(rowBase + row) * N + s * 128;
        float sl = 0.f, sr = 0.f;
#pragma unroll
        for (int c8 = 0; c8 < 16; c8++) {
            bf8 v = *(const bf8*)(crow + c8 * 8);
            int cb = s * 128 + c8 * 8;
#pragma unroll
            for (int j = 0; j < 8; j++) {
                float f = bf2f(v[j]);
                sl += f * alds[cb + j];
                sr += f * alds[512 + cb + j];
            }
        }
        el[(rowBase + row) * 4 + s] = sl;
        if (rowBase + row < ndst) er[(rowBase + row) * 4 + s] = sr;
    }
}

// ---- s[i] = sum of first count coeffs ----
__global__ __launch_bounds__(256) void k_s(const float* __restrict__ poi_coeff,
                                           const int* __restrict__ out_nodes,
                                           const int* __restrict__ ncounts,
                                           float* __restrict__ s) {
    int wv = threadIdx.x >> 6, lane = threadIdx.x & 63;
    int i = blockIdx.x * 4 + wv;
    int nid = out_nodes[i];
    int cnt = ncounts[nid];
    float v = (lane < cnt && lane < KNB) ? poi_coeff[(size_t)nid * KNB + lane] : 0.f;
    for (int m = 1; m < 64; m <<= 1) v += __shfl_xor(v, m);
    if (lane == 0) s[i] = v;
}

// ---- wave-per-dst softmax + aggregation + epilogue (no barriers) ----
__global__ __launch_bounds__(256) void k_agg(const int* __restrict__ offsets,
                                             const int* __restrict__ edge_ids,
                                             const int* __restrict__ src_idx,
                                             const float* __restrict__ el,
                                             const float* __restrict__ er,
                                             const short* __restrict__ feat_src,
                                             const short* __restrict__ res,
                                             const float* __restrict__ bias,
                                             const short* __restrict__ fdist,
                                             float* __restrict__ out) {
    int wv = threadIdx.x >> 6, lane = threadIdx.x & 63;
    int d = blockIdx.x * 4 + wv;
    int start = offsets[d];
    int cnt = offsets[d + 1] - start;
    float4 erv = *(const float4*)(er + (size_t)d * 4);
    float er0 = erv.x, er1 = erv.y, er2 = erv.z, er3 = erv.w;

    // chunk-0 leaky values cached in regs
    int srow0 = 0;
    float v0 = -1e30f, v1 = -1e30f, v2 = -1e30f, v3 = -1e30f;
    if (lane < cnt) {
        int e = edge_ids[start + lane];
        srow0 = src_idx[e];
        float4 lv = *(const float4*)(el + (size_t)srow0 * 4);
        v0 = lv.x + er0; v0 = v0 > 0 ? v0 : NEG * v0;
        v1 = lv.y + er1; v1 = v1 > 0 ? v1 : NEG * v1;
        v2 = lv.z + er2; v2 = v2 > 0 ? v2 : NEG * v2;
        v3 = lv.w + er3; v3 = v3 > 0 ? v3 : NEG * v3;
    }
    float m0 = v0, m1 = v1, m2 = v2, m3 = v3;
    for (int base = 64; base < cnt; base += 64) {
        if (base + lane < cnt) {
            int e = edge_ids[start + base + lane];
            int s = src_idx[e];
            float4 lv = *(const float4*)(el + (size_t)s * 4);
            float w0 = lv.x + er0; w0 = w0 > 0 ? w0 : NEG * w0; m0 = fmaxf(m0, w0);
            float w1 = lv.y + er1; w1 = w1 > 0 ? w1 : NEG * w1; m1 = fmaxf(m1, w1);
            float w2 = lv.z + er2; w2 = w2 > 0 ? w2 : NEG * w2; m2 = fmaxf(m2, w2);
            float w3 = lv.w + er3; w3 = w3 > 0 ? w3 : NEG * w3; m3 = fmaxf(m3, w3);
        }
    }
    for (int sh = 1; sh < 64; sh <<= 1) {
        m0 = fmaxf(m0, __shfl_xor(m0, sh)); m1 = fmaxf(m1, __shfl_xor(m1, sh));
        m2 = fmaxf(m2, __shfl_xor(m2, sh)); m3 = fmaxf(m3, __shfl_xor(m3, sh));
    }
    // denom
    float s0 = 0.f, s1 = 0.f, s2 = 0.f, s3 = 0.f;
    if (lane < cnt) {
        s0 = __expf(v0 - m0); s1 = __expf(v1 - m1);
        s2 = __expf(v2 - m2); s3 = __expf(v3 - m3);
    }
    for (int base = 64; base < cnt; base += 64) {
        if (base + lane < cnt) {
            int e = edge_ids[start + base + lane];
            int s = src_idx[e];
            float4 lv = *(const float4*)(el + (size_t)s * 4);
            float w0 = lv.x + er0; w0 = w0 > 0 ? w0 : NEG * w0; s0 += __expf(w0 - m0);
            float w1 = lv.y + er1; w1 = w1 > 0 ? w1 : NEG * w1; s1 += __expf(w1 - m1);
            float w2 = lv.z + er2; w2 = w2 > 0 ? w2 : NEG * w2; s2 += __expf(w2 - m2);
            float w3 = lv.w + er3; w3 = w3 > 0 ? w3 : NEG * w3; s3 += __expf(w3 - m3);
        }
    }
    for (int sh = 1; sh < 64; sh <<= 1) {
        s0 += __shfl_xor(s0, sh); s1 += __shfl_xor(s1, sh);
        s2 += __shfl_xor(s2, sh); s3 += __shfl_xor(s3, sh);
    }
    float i0 = 1.f / fmaxf(s0, 1e-9f), i1 = 1.f / fmaxf(s1, 1e-9f);
    float i2 = 1.f / fmaxf(s2, 1e-9f), i3 = 1.f / fmaxf(s3, 1e-9f);

    // pass C: lane owns 8 contiguous cols (one head)
    float acc[8] = {0.f, 0.f, 0.f, 0.f, 0.f, 0.f, 0.f, 0.f};
    int c0 = lane * 8;
    int myh = lane >> 4;
    for (int base = 0; base < cnt; base += 64) {
        int nc = min(64, cnt - base);
        float a0, a1, a2, a3; int sr_;
        if (base == 0) {
            sr_ = srow0;
            a0 = __expf(v0 - m0) * i0; a1 = __expf(v1 - m1) * i1;
            a2 = __expf(v2 - m2) * i2; a3 = __expf(v3 - m3) * i3;
        } else {
            sr_ = 0; a0 = a1 = a2 = a3 = 0.f;
            if (base + lane < cnt) {
                int e = edge_ids[start + base + lane];
                sr_ = src_idx[e];
                float4 lv = *(const float4*)(el + (size_t)sr_ * 4);
                float w0 = lv.x + er0; w0 = w0 > 0 ? w0 : NEG * w0; a0 = __expf(w0 - m0) * i0;
                float w1 = lv.y + er1; w1 = w1 > 0 ? w1 : NEG * w1; a1 = __expf(w1 - m1) * i1;
                float w2 = lv.z + er2; w2 = w2 > 0 ? w2 : NEG * w2; a2 = __expf(w2 - m2) * i2;
                float w3 = lv.w + er3; w3 = w3 > 0 ? w3 : NEG * w3; a3 = __expf(w3 - m3) * i3;
            }
        }
        for (int c = 0; c < nc; c++) {
            int srw = __shfl(sr_, c);
            float b0 = __shfl(a0, c), b1 = __shfl(a1, c);
            float b2 = __shfl(a2, c), b3 = __shfl(a3, c);
            float af = myh == 0 ? b0 : (myh == 1 ? b1 : (myh == 2 ? b2 : b3));
            bf8 v = *(const bf8*)(feat_src + (size_t)srw * 512 + c0);
#pragma unroll
            for (int j = 0; j < 8; j++) acc[j] += af * bf2f(v[j]);
        }
    }

    // epilogue
    bf8 rv = *(const bf8*)(res + (size_t)d * 512 + c0);
    float4 bv0 = *(const float4*)(bias + c0);
    float4 bv1 = *(const float4*)(bias + c0 + 4);
    float bb[8] = {bv0.x, bv0.y, bv0.z, bv0.w, bv1.x, bv1.y, bv1.z, bv1.w};
    bf8 fv = *(const bf8*)(fdist + (size_t)d * HID + (c0 & 127));
    float o[8];
#pragma unroll
    for (int j = 0; j < 8; j++) {
        float g = acc[j] + bf2f(rv[j]) + bb[j];
        g = g > 0 ? g : expm1f(g);
        float v = (g + bf2f(fv[j])) * 0.5f;
        o[j] = v > 0 ? v : 0.f;
    }
    float* op = out + (size_t)d * 512 + c0;
    *(float4*)op = make_float4(o[0], o[1], o[2], o[3]);
    *(float4*)(op + 4) = make_float4(o[4], o[5], o[6], o[7]);
}

extern "C" void kernel_launch(void* const* d_in, const int* in_sizes, int n_in,
                              void* d_out, int out_size, void* d_ws, size_t ws_size,
                              hipStream_t stream) {
    const float* feat      = (const float*)d_in[0];
    const float* poi_cat   = (const float*)d_in[1];
    const float* poi_coeff = (const float*)d_in[2];
    const float* fc_w      = (const float*)d_in[3];
    const float* attn_l    = (const float*)d_in[4];
    const float* attn_r    = (const float*)d_in[5];
    const float* bias_p    = (const float*)d_in[6];
    const float* res_w     = (const float*)d_in[7];
    const float* w_w       = (const float*)d_in[8];
    const int* src_idx     = (const int*)d_in[9];
    const int* dst_idx     = (const int*)d_in[10];
    const int* out_nodes   = (const int*)d_in[11];
    const int* ncounts     = (const int*)d_in[12];
    float* out = (float*)d_out;

    char* w = (char*)d_ws;
    auto alloc = [&](size_t bytes) -> char* {
        char* p = w; w += (bytes + 255) & ~(size_t)255; return p;
    };
    short* feat_bf  = (short*)alloc((size_t)N_SRC * FIN * 2);
    short* fcw_bf   = (short*)alloc((size_t)512 * FIN * 2);
    short* resw_bf  = (short*)alloc((size_t)512 * FIN * 2);
    short* ww_bf    = (short*)alloc((size_t)HID * FIN * 2);
    short* cf_bf    = (short*)alloc((size_t)N_DST * FIN * 2);
    short* feat_src = (short*)alloc((size_t)N_SRC * 512 * 2);
    short* res      = (short*)alloc((size_t)N_DST * 512 * 2);
    short* fdist    = (short*)alloc((size_t)N_DST * HID * 2);
    float* el       = (float*)alloc((size_t)N_SRC * 4 * 4);
    float* er       = (float*)alloc((size_t)N_DST * 4 * 4);
    float* sArr     = (float*)alloc((size_t)N_DST * 4);
    int* counts     = (int*)alloc((size_t)N_DST * 4);
    int* offsets    = (int*)alloc((size_t)(N_DST + 1) * 4);
    int* cursor     = (int*)alloc((size_t)N_DST * 4);
    int* edge_ids   = (int*)alloc((size_t)NEDGE * 4);

    hipMemsetAsync(counts, 0, N_DST * 4, stream);

    k_f2bf<<<N_SRC * FIN / 4 / 256, 256, 0, stream>>>(feat, feat_bf, N_SRC * FIN / 4);
    k_prep_w<<<288, 256, 0, stream>>>(fc_w, res_w, w_w, fcw_bf, resw_bf, ww_bf);
    k_gather_cf<<<N_DST * 64 / 256, 256, 0, stream>>>(poi_cat, out_nodes, cf_bf);

    k_hist<<<NEDGE / 256, 256, 0, stream>>>(dst_idx, counts);
    k_scan<<<1, 1024, 0, stream>>>(counts, offsets, cursor);
    k_scatter<<<NEDGE / 256, 256, 0, stream>>>(dst_idx, cursor, edge_ids);
    k_s<<<N_DST / 4, 256, 0, stream>>>(poi_coeff, out_nodes, ncounts, sArr);

    // feat_src = feat @ fc_w.T (+fused el/er)
    k_gemm<<<N_SRC / 64, 256, 0, stream>>>(feat_bf, fcw_bf, feat_src, nullptr, 512, 8, 1,
                                           attn_l, attn_r, el, er, N_DST);
    // res = feat[:N_DST] @ res_w.T
    k_gemm<<<N_DST / 64, 256, 0, stream>>>(feat_bf, resw_bf, res, nullptr, 512, 8, 0,
                                           nullptr, nullptr, nullptr, nullptr, 0);
    // fdist = (cf @ w_w.T) * s
    k_gemm<<<N_DST / 64, 256, 0, stream>>>(cf_bf, ww_bf, fdist, sArr, 128, 2, 0,
                                           nullptr, nullptr, nullptr, nullptr, 0);

    k_agg<<<N_DST / 4, 256, 0, stream>>>(offsets, edge_ids, src_idx, el, er, feat_src,
                                         res, bias_p, fdist, out);
}

// Round 3
// 366.165 us; speedup vs baseline: 1.2357x; 1.1442x over previous
//
#include <hip/hip_runtime.h>

#define N_SRC 65536
#define N_DST 16384
#define NEDGE 262144
#define FIN 256
#define HID 128
#define KNB 50
#define NEG 0.2f

typedef short bf8 __attribute__((ext_vector_type(8)));
typedef float f32x4 __attribute__((ext_vector_type(4)));

static __device__ __forceinline__ short f2bf(float f) {
    union { float f; unsigned u; } v; v.f = f;
    unsigned r = v.u + 0x7fffu + ((v.u >> 16) & 1u);
    return (short)(r >> 16);
}
static __device__ __forceinline__ float bf2f(short b) {
    union { unsigned u; float f; } v; v.u = ((unsigned)(unsigned short)b) << 16;
    return v.f;
}

// ---- feat fp32 -> bf16 ----
__global__ void k_f2bf(const float* __restrict__ in, short* __restrict__ out, int n4) {
    int i = blockIdx.x * blockDim.x + threadIdx.x;
    if (i >= n4) return;
    float4 v = ((const float4*)in)[i];
    short4 o; o.x = f2bf(v.x); o.y = f2bf(v.y); o.z = f2bf(v.z); o.w = f2bf(v.w);
    ((short4*)out)[i] = o;
}

// ---- all three weight matrices -> bf16 in one launch ----
__global__ void k_prep_w(const float* __restrict__ fc, const float* __restrict__ rw,
                         const float* __restrict__ ww, short* __restrict__ fco,
                         short* __restrict__ rwo, short* __restrict__ wwo) {
    int i = blockIdx.x * 256 + threadIdx.x;
    const float* src; short* dst; int off;
    if (i < 32768) { src = fc; dst = fco; off = i; }
    else if (i < 65536) { src = rw; dst = rwo; off = i - 32768; }
    else { src = ww; dst = wwo; off = i - 65536; }
    float4 v = ((const float4*)src)[off];
    short4 o; o.x = f2bf(v.x); o.y = f2bf(v.y); o.z = f2bf(v.z); o.w = f2bf(v.w);
    ((short4*)dst)[off] = o;
}

// ---- gather poi_cat_feat[output_nodes] -> bf16 [N_DST,256] ----
__global__ void k_gather_cf(const float* __restrict__ poi, const int* __restrict__ nodes,
                            short* __restrict__ cf) {
    int i = blockIdx.x * blockDim.x + threadIdx.x;
    int row = i >> 6, c4 = i & 63;
    int nid = nodes[row];
    float4 v = ((const float4*)(poi + (size_t)nid * FIN))[c4];
    short4 o; o.x = f2bf(v.x); o.y = f2bf(v.y); o.z = f2bf(v.z); o.w = f2bf(v.w);
    ((short4*)(cf + (size_t)row * FIN))[c4] = o;
}

// ---- CSR build ----
__global__ void k_hist(const int* __restrict__ dst, int* __restrict__ counts) {
    int e = blockIdx.x * blockDim.x + threadIdx.x;
    if (e < NEDGE) atomicAdd(&counts[dst[e]], 1);
}

__global__ void k_scan(const int* __restrict__ counts, int* __restrict__ offsets,
                       int* __restrict__ cursor) {
    __shared__ int part[1024];
    int t = threadIdx.x;
    int base = t * 16;
    int loc[16]; int s = 0;
    for (int i = 0; i < 16; i++) { loc[i] = counts[base + i]; s += loc[i]; }
    part[t] = s; __syncthreads();
    for (int off = 1; off < 1024; off <<= 1) {
        int v = (t >= off) ? part[t - off] : 0;
        __syncthreads();
        part[t] += v;
        __syncthreads();
    }
    int run = (t == 0) ? 0 : part[t - 1];
    for (int i = 0; i < 16; i++) { offsets[base + i] = run; cursor[base + i] = run; run += loc[i]; }
    if (t == 1023) offsets[N_DST] = run;
}

__global__ void k_scatter(const int* __restrict__ dst, int* __restrict__ cursor,
                          int* __restrict__ edge_ids) {
    int e = blockIdx.x * blockDim.x + threadIdx.x;
    if (e < NEDGE) {
        int d = dst[e];
        int pos = atomicAdd(&cursor[d], 1);
        edge_ids[pos] = e;
    }
}

// ---- m97-style bf16 MFMA GEMM: C[M,N] = A[M,256] @ W[N,256]^T ----
// 128x128 block tile, BK=64, A+B staged in LDS via global_load_lds(16B) with
// XOR granule swizzle (c ^= r&7) -> all ds_read_b128 frag reads 2-way (free).
// Wave tile 32 rows x 128 cols (head-aligned when N=512) so el/er is computed
// straight from the accumulators (no LDS, no C re-read).
__global__ __launch_bounds__(256, 3) void k_gemm(
    const short* __restrict__ A, const short* __restrict__ W, short* __restrict__ C,
    const float* __restrict__ scale, int N, int do_elr,
    const float* __restrict__ attn_l, const float* __restrict__ attn_r,
    float* __restrict__ el, float* __restrict__ er, int ndst) {
    __shared__ __align__(16) short Abuf[128 * 64];
    __shared__ __align__(16) short Bbuf[128 * 64];
    int t = threadIdx.x, wv = t >> 6, lane = t & 63;
    int l15 = lane & 15, quad = lane >> 4;
    int rowBase = blockIdx.y * 128, colBase = blockIdx.x * 128;
    // staging: waves 0-1 -> A slabs 0..15, waves 2-3 -> B slabs 0..15
    const short* sbase = (wv < 2) ? (A + (size_t)rowBase * FIN)
                                  : (W + (size_t)colBase * FIN);
    short* dbase = (wv < 2) ? Abuf : Bbuf;
    int s0 = (wv & 1) * 8;
    int rsub = lane >> 3;                 // 0..7
    int cg = (lane & 7) ^ rsub;           // swizzled source granule

    f32x4 acc[2][8] = {};
    for (int kb = 0; kb < 4; kb++) {
#pragma unroll
        for (int q = 0; q < 8; q++) {
            int slab = s0 + q;
            int r_loc = slab * 8 + rsub;
            __builtin_amdgcn_global_load_lds(
                (const __attribute__((address_space(1))) void*)(sbase + (size_t)r_loc * FIN + kb * 64 + cg * 8),
                (__attribute__((address_space(3))) void*)(dbase + slab * 512), 16, 0, 0);
        }
        __syncthreads();
#pragma unroll
        for (int kk = 0; kk < 2; kk++) {
            int gidx = (quad + kk * 4) ^ (l15 & 7);
            bf8 a[2], b[8];
#pragma unroll
            for (int i = 0; i < 2; i++) {
                int row = wv * 32 + i * 16 + l15;
                a[i] = *(const bf8*)(Abuf + (row * 8 + gidx) * 8);
            }
#pragma unroll
            for (int j = 0; j < 8; j++) {
                int row = j * 16 + l15;
                b[j] = *(const bf8*)(Bbuf + (row * 8 + gidx) * 8);
            }
#pragma unroll
            for (int i = 0; i < 2; i++)
#pragma unroll
                for (int j = 0; j < 8; j++)
                    acc[i][j] = __builtin_amdgcn_mfma_f32_16x16x32_bf16(a[i], b[j], acc[i][j], 0, 0, 0);
        }
        if (kb < 3) __syncthreads();
    }
    // store C (+optional row scale)
#pragma unroll
    for (int i = 0; i < 2; i++)
#pragma unroll
        for (int r = 0; r < 4; r++) {
            int row = rowBase + wv * 32 + i * 16 + quad * 4 + r;
            float sc = scale ? scale[row] : 1.0f;
#pragma unroll
            for (int j = 0; j < 8; j++)
                C[(size_t)row * N + colBase + j * 16 + l15] = f2bf(acc[i][j][r] * sc);
        }
    if (do_elr) {
        int h = blockIdx.x;   // col tile == head (N=512, 128 cols per head)
        float alv[8], arv[8];
#pragma unroll
        for (int j = 0; j < 8; j++) {
            alv[j] = attn_l[h * HID + j * 16 + l15];
            arv[j] = attn_r[h * HID + j * 16 + l15];
        }
#pragma unroll
        for (int i = 0; i < 2; i++)
#pragma unroll
            for (int r = 0; r < 4; r++) {
                float dl = 0.f, dr = 0.f;
#pragma unroll
                for (int j = 0; j < 8; j++) {
                    float c = acc[i][j][r];
                    dl += c * alv[j];
                    dr += c * arv[j];
                }
                dl += __shfl_xor(dl, 1); dr += __shfl_xor(dr, 1);
                dl += __shfl_xor(dl, 2); dr += __shfl_xor(dr, 2);
                dl += __shfl_xor(dl, 4); dr += __shfl_xor(dr, 4);
                dl += __shfl_xor(dl, 8); dr += __shfl_xor(dr, 8);
                if (l15 == 0) {
                    int row = rowBase + wv * 32 + i * 16 + quad * 4 + r;
                    el[row * 4 + h] = dl;
                    if (row < ndst) er[row * 4 + h] = dr;
                }
            }
    }
}

// ---- s[i] = sum of first count coeffs ----
__global__ __launch_bounds__(256) void k_s(const float* __restrict__ poi_coeff,
                                           const int* __restrict__ out_nodes,
                                           const int* __restrict__ ncounts,
                                           float* __restrict__ s) {
    int wv = threadIdx.x >> 6, lane = threadIdx.x & 63;
    int i = blockIdx.x * 4 + wv;
    int nid = out_nodes[i];
    int cnt = ncounts[nid];
    float v = (lane < cnt && lane < KNB) ? poi_coeff[(size_t)nid * KNB + lane] : 0.f;
    for (int m = 1; m < 64; m <<= 1) v += __shfl_xor(v, m);
    if (lane == 0) s[i] = v;
}

// ---- wave-per-dst softmax + aggregation + epilogue (no barriers) ----
__global__ __launch_bounds__(256) void k_agg(const int* __restrict__ offsets,
                                             const int* __restrict__ edge_ids,
                                             const int* __restrict__ src_idx,
                                             const float* __restrict__ el,
                                             const float* __restrict__ er,
                                             const short* __restrict__ feat_src,
                                             const short* __restrict__ res,
                                             const float* __restrict__ bias,
                                             const short* __restrict__ fdist,
                                             float* __restrict__ out) {
    int wv = threadIdx.x >> 6, lane = threadIdx.x & 63;
    int d = blockIdx.x * 4 + wv;
    int start = offsets[d];
    int cnt = offsets[d + 1] - start;
    float4 erv = *(const float4*)(er + (size_t)d * 4);
    float er0 = erv.x, er1 = erv.y, er2 = erv.z, er3 = erv.w;

    int srow0 = 0;
    float v0 = -1e30f, v1 = -1e30f, v2 = -1e30f, v3 = -1e30f;
    if (lane < cnt) {
        int e = edge_ids[start + lane];
        srow0 = src_idx[e];
        float4 lv = *(const float4*)(el + (size_t)srow0 * 4);
        v0 = lv.x + er0; v0 = v0 > 0 ? v0 : NEG * v0;
        v1 = lv.y + er1; v1 = v1 > 0 ? v1 : NEG * v1;
        v2 = lv.z + er2; v2 = v2 > 0 ? v2 : NEG * v2;
        v3 = lv.w + er3; v3 = v3 > 0 ? v3 : NEG * v3;
    }
    float m0 = v0, m1 = v1, m2 = v2, m3 = v3;
    for (int base = 64; base < cnt; base += 64) {
        if (base + lane < cnt) {
            int e = edge_ids[start + base + lane];
            int s = src_idx[e];
            float4 lv = *(const float4*)(el + (size_t)s * 4);
            float w0 = lv.x + er0; w0 = w0 > 0 ? w0 : NEG * w0; m0 = fmaxf(m0, w0);
            float w1 = lv.y + er1; w1 = w1 > 0 ? w1 : NEG * w1; m1 = fmaxf(m1, w1);
            float w2 = lv.z + er2; w2 = w2 > 0 ? w2 : NEG * w2; m2 = fmaxf(m2, w2);
            float w3 = lv.w + er3; w3 = w3 > 0 ? w3 : NEG * w3; m3 = fmaxf(m3, w3);
        }
    }
    for (int sh = 1; sh < 64; sh <<= 1) {
        m0 = fmaxf(m0, __shfl_xor(m0, sh)); m1 = fmaxf(m1, __shfl_xor(m1, sh));
        m2 = fmaxf(m2, __shfl_xor(m2, sh)); m3 = fmaxf(m3, __shfl_xor(m3, sh));
    }
    float s0 = 0.f, s1 = 0.f, s2 = 0.f, s3 = 0.f;
    if (lane < cnt) {
        s0 = __expf(v0 - m0); s1 = __expf(v1 - m1);
        s2 = __expf(v2 - m2); s3 = __expf(v3 - m3);
    }
    for (int base = 64; base < cnt; base += 64) {
        if (base + lane < cnt) {
            int e = edge_ids[start + base + lane];
            int s = src_idx[e];
            float4 lv = *(const float4*)(el + (size_t)s * 4);
            float w0 = lv.x + er0; w0 = w0 > 0 ? w0 : NEG * w0; s0 += __expf(w0 - m0);
            float w1 = lv.y + er1; w1 = w1 > 0 ? w1 : NEG * w1; s1 += __expf(w1 - m1);
            float w2 = lv.z + er2; w2 = w2 > 0 ? w2 : NEG * w2; s2 += __expf(w2 - m2);
            float w3 = lv.w + er3; w3 = w3 > 0 ? w3 : NEG * w3; s3 += __expf(w3 - m3);
        }
    }
    for (int sh = 1; sh < 64; sh <<= 1) {
        s0 += __shfl_xor(s0, sh); s1 += __shfl_xor(s1, sh);
        s2 += __shfl_xor(s2, sh); s3 += __shfl_xor(s3, sh);
    }
    float i0 = 1.f / fmaxf(s0, 1e-9f), i1 = 1.f / fmaxf(s1, 1e-9f);
    float i2 = 1.f / fmaxf(s2, 1e-9f), i3 = 1.f / fmaxf(s3, 1e-9f);

    float acc[8] = {0.f, 0.f, 0.f, 0.f, 0.f, 0.f, 0.f, 0.f};
    int c0 = lane * 8;
    int myh = lane >> 4;
    for (int base = 0; base < cnt; base += 64) {
        int nc = min(64, cnt - base);
        float a0, a1, a2, a3; int sr_;
        if (base == 0) {
            sr_ = srow0;
            a0 = __expf(v0 - m0) * i0; a1 = __expf(v1 - m1) * i1;
            a2 = __expf(v2 - m2) * i2; a3 = __expf(v3 - m3) * i3;
        } else {
            sr_ = 0; a0 = a1 = a2 = a3 = 0.f;
            if (base + lane < cnt) {
                int e = edge_ids[start + base + lane];
                sr_ = src_idx[e];
                float4 lv = *(const float4*)(el + (size_t)sr_ * 4);
                float w0 = lv.x + er0; w0 = w0 > 0 ? w0 : NEG * w0; a0 = __expf(w0 - m0) * i0;
                float w1 = lv.y + er1; w1 = w1 > 0 ? w1 : NEG * w1; a1 = __expf(w1 - m1) * i1;
                float w2 = lv.z + er2; w2 = w2 > 0 ? w2 : NEG * w2; a2 = __expf(w2 - m2) * i2;
                float w3 = lv.w + er3; w3 = w3 > 0 ? w3 : NEG * w3; a3 = __expf(w3 - m3) * i3;
            }
        }
        for (int c = 0; c < nc; c++) {
            int srw = __shfl(sr_, c);
            float b0 = __shfl(a0, c), b1 = __shfl(a1, c);
            float b2 = __shfl(a2, c), b3 = __shfl(a3, c);
            float af = myh == 0 ? b0 : (myh == 1 ? b1 : (myh == 2 ? b2 : b3));
            bf8 v = *(const bf8*)(feat_src + (size_t)srw * 512 + c0);
#pragma unroll
            for (int j = 0; j < 8; j++) acc[j] += af * bf2f(v[j]);
        }
    }

    bf8 rv = *(const bf8*)(res + (size_t)d * 512 + c0);
    float4 bv0 = *(const float4*)(bias + c0);
    float4 bv1 = *(const float4*)(bias + c0 + 4);
    float bb[8] = {bv0.x, bv0.y, bv0.z, bv0.w, bv1.x, bv1.y, bv1.z, bv1.w};
    bf8 fv = *(const bf8*)(fdist + (size_t)d * HID + (c0 & 127));
    float o[8];
#pragma unroll
    for (int j = 0; j < 8; j++) {
        float g = acc[j] + bf2f(rv[j]) + bb[j];
        g = g > 0 ? g : expm1f(g);
        float v = (g + bf2f(fv[j])) * 0.5f;
        o[j] = v > 0 ? v : 0.f;
    }
    float* op = out + (size_t)d * 512 + c0;
    *(float4*)op = make_float4(o[0], o[1], o[2], o[3]);
    *(float4*)(op + 4) = make_float4(o[4], o[5], o[6], o[7]);
}

extern "C" void kernel_launch(void* const* d_in, const int* in_sizes, int n_in,
                              void* d_out, int out_size, void* d_ws, size_t ws_size,
                              hipStream_t stream) {
    const float* feat      = (const float*)d_in[0];
    const float* poi_cat   = (const float*)d_in[1];
    const float* poi_coeff = (const float*)d_in[2];
    const float* fc_w      = (const float*)d_in[3];
    const float* attn_l    = (const float*)d_in[4];
    const float* attn_r    = (const float*)d_in[5];
    const float* bias_p    = (const float*)d_in[6];
    const float* res_w     = (const float*)d_in[7];
    const float* w_w       = (const float*)d_in[8];
    const int* src_idx     = (const int*)d_in[9];
    const int* dst_idx     = (const int*)d_in[10];
    const int* out_nodes   = (const int*)d_in[11];
    const int* ncounts     = (const int*)d_in[12];
    float* out = (float*)d_out;

    char* w = (char*)d_ws;
    auto alloc = [&](size_t bytes) -> char* {
        char* p = w; w += (bytes + 255) & ~(size_t)255; return p;
    };
    short* feat_bf  = (short*)alloc((size_t)N_SRC * FIN * 2);
    short* fcw_bf   = (short*)alloc((size_t)512 * FIN * 2);
    short* resw_bf  = (short*)alloc((size_t)512 * FIN * 2);
    short* ww_bf    = (short*)alloc((size_t)HID * FIN * 2);
    short* cf_bf    = (short*)alloc((size_t)N_DST * FIN * 2);
    short* feat_src = (short*)alloc((size_t)N_SRC * 512 * 2);
    short* res      = (short*)alloc((size_t)N_DST * 512 * 2);
    short* fdist    = (short*)alloc((size_t)N_DST * HID * 2);
    float* el       = (float*)alloc((size_t)N_SRC * 4 * 4);
    float* er       = (float*)alloc((size_t)N_DST * 4 * 4);
    float* sArr     = (float*)alloc((size_t)N_DST * 4);
    int* counts     = (int*)alloc((size_t)N_DST * 4);
    int* offsets    = (int*)alloc((size_t)(N_DST + 1) * 4);
    int* cursor     = (int*)alloc((size_t)N_DST * 4);
    int* edge_ids   = (int*)alloc((size_t)NEDGE * 4);

    hipMemsetAsync(counts, 0, N_DST * 4, stream);

    k_f2bf<<<N_SRC * FIN / 4 / 256, 256, 0, stream>>>(feat, feat_bf, N_SRC * FIN / 4);
    k_prep_w<<<288, 256, 0, stream>>>(fc_w, res_w, w_w, fcw_bf, resw_bf, ww_bf);
    k_gather_cf<<<N_DST * 64 / 256, 256, 0, stream>>>(poi_cat, out_nodes, cf_bf);

    k_hist<<<NEDGE / 256, 256, 0, stream>>>(dst_idx, counts);
    k_scan<<<1, 1024, 0, stream>>>(counts, offsets, cursor);
    k_scatter<<<NEDGE / 256, 256, 0, stream>>>(dst_idx, cursor, edge_ids);
    k_s<<<N_DST / 4, 256, 0, stream>>>(poi_coeff, out_nodes, ncounts, sArr);

    // feat_src = feat @ fc_w.T (+fused el/er from accumulators)
    k_gemm<<<dim3(4, N_SRC / 128), 256, 0, stream>>>(feat_bf, fcw_bf, feat_src, nullptr, 512, 1,
                                                     attn_l, attn_r, el, er, N_DST);
    // res = feat[:N_DST] @ res_w.T
    k_gemm<<<dim3(4, N_DST / 128), 256, 0, stream>>>(feat_bf, resw_bf, res, nullptr, 512, 0,
                                                     nullptr, nullptr, nullptr, nullptr, 0);
    // fdist = (cf @ w_w.T) * s
    k_gemm<<<dim3(1, N_DST / 128), 256, 0, stream>>>(cf_bf, ww_bf, fdist, sArr, 128, 0,
                                                     nullptr, nullptr, nullptr, nullptr, 0);

    k_agg<<<N_DST / 4, 256, 0, stream>>>(offsets, edge_ids, src_idx, el, er, feat_src,
                                         res, bias_p, fdist, out);
}

// Round 5
// 353.472 us; speedup vs baseline: 1.2801x; 1.0359x over previous
//
#include <hip/hip_runtime.h>

#define N_SRC 65536
#define N_DST 16384
#define NEDGE 262144
#define FIN 256
#define HID 128
#define KNB 50
#define NEG 0.2f

typedef short bf8 __attribute__((ext_vector_type(8)));
typedef float f32x4 __attribute__((ext_vector_type(4)));

static __device__ __forceinline__ short f2bf(float f) {
    union { float f; unsigned u; } v; v.f = f;
    unsigned r = v.u + 0x7fffu + ((v.u >> 16) & 1u);
    return (short)(r >> 16);
}
static __device__ __forceinline__ float bf2f(short b) {
    union { unsigned u; float f; } v; v.u = ((unsigned)(unsigned short)b) << 16;
    return v.f;
}

// ---- feat fp32 -> bf16 ----
__global__ void k_f2bf(const float* __restrict__ in, short* __restrict__ out, int n4) {
    int i = blockIdx.x * blockDim.x + threadIdx.x;
    if (i >= n4) return;
    float4 v = ((const float4*)in)[i];
    short4 o; o.x = f2bf(v.x); o.y = f2bf(v.y); o.z = f2bf(v.z); o.w = f2bf(v.w);
    ((short4*)out)[i] = o;
}

// ---- all three weight matrices -> bf16 in one launch ----
__global__ void k_prep_w(const float* __restrict__ fc, const float* __restrict__ rw,
                         const float* __restrict__ ww, short* __restrict__ fco,
                         short* __restrict__ rwo, short* __restrict__ wwo) {
    int i = blockIdx.x * 256 + threadIdx.x;
    const float* src; short* dst; int off;
    if (i < 32768) { src = fc; dst = fco; off = i; }
    else if (i < 65536) { src = rw; dst = rwo; off = i - 32768; }
    else { src = ww; dst = wwo; off = i - 65536; }
    float4 v = ((const float4*)src)[off];
    short4 o; o.x = f2bf(v.x); o.y = f2bf(v.y); o.z = f2bf(v.z); o.w = f2bf(v.w);
    ((short4*)dst)[off] = o;
}

// ---- wave-per-dst-row: gather poi_cat_feat[output_nodes] -> bf16 AND s[] sum ----
__global__ __launch_bounds__(256) void k_prep_dst(
    const float* __restrict__ poi, const float* __restrict__ poi_coeff,
    const int* __restrict__ nodes, const int* __restrict__ ncounts,
    short* __restrict__ cf, float* __restrict__ sArr) {
    int wv = threadIdx.x >> 6, lane = threadIdx.x & 63;
    int row = blockIdx.x * 4 + wv;
    int nid = nodes[row];
    float4 v = ((const float4*)(poi + (size_t)nid * FIN))[lane];
    short4 o; o.x = f2bf(v.x); o.y = f2bf(v.y); o.z = f2bf(v.z); o.w = f2bf(v.w);
    ((short4*)(cf + (size_t)row * FIN))[lane] = o;
    int cnt = ncounts[nid];
    float s = (lane < cnt && lane < KNB) ? poi_coeff[(size_t)nid * KNB + lane] : 0.f;
    for (int m = 1; m < 64; m <<= 1) s += __shfl_xor(s, m);
    if (lane == 0) sArr[row] = s;
}

// ---- CSR build ----
__global__ void k_hist(const int* __restrict__ dst, int* __restrict__ counts) {
    int e = blockIdx.x * blockDim.x + threadIdx.x;
    if (e < NEDGE) atomicAdd(&counts[dst[e]], 1);
}

// R3-proven Hillis-Steele scan (reverted from R4's shuffle scan as insurance)
__global__ void k_scan(const int* __restrict__ counts, int* __restrict__ offsets,
                       int* __restrict__ cursor) {
    __shared__ int part[1024];
    int t = threadIdx.x;
    int base = t * 16;
    int loc[16]; int s = 0;
    for (int i = 0; i < 16; i++) { loc[i] = counts[base + i]; s += loc[i]; }
    part[t] = s; __syncthreads();
    for (int off = 1; off < 1024; off <<= 1) {
        int v = (t >= off) ? part[t - off] : 0;
        __syncthreads();
        part[t] += v;
        __syncthreads();
    }
    int run = (t == 0) ? 0 : part[t - 1];
    for (int i = 0; i < 16; i++) { offsets[base + i] = run; cursor[base + i] = run; run += loc[i]; }
    if (t == 1023) offsets[N_DST] = run;
}

__global__ void k_scatter(const int* __restrict__ dst, int* __restrict__ cursor,
                          int* __restrict__ edge_ids) {
    int e = blockIdx.x * blockDim.x + threadIdx.x;
    if (e < NEDGE) {
        int d = dst[e];
        int pos = atomicAdd(&cursor[d], 1);
        edge_ids[pos] = e;
    }
}

// ---- merged MFMA GEMM: all 3 matmuls in one 2688-block launch ----
// blocks [0,2048): feat_src = feat@fc_w.T (+el/er epilogue from accumulators)
// blocks [2048,2560): res = feat[:Ndst]@res_w.T
// blocks [2560,2688): fdist = (cf@w_w.T)*s
// 128x128 tile, BK=64, A+B in LDS via global_load_lds(16B), XOR granule swizzle.
// NOTE: explicit vmcnt(0) drain before the barrier — do NOT rely on the
// compiler emitting it through the role-decode control flow (R4 regression).
__global__ __launch_bounds__(256, 3) void k_gemm_all(
    const short* __restrict__ feat_bf, const short* __restrict__ fcw,
    const short* __restrict__ resw, const short* __restrict__ ww,
    const short* __restrict__ cf_bf, short* __restrict__ feat_src,
    short* __restrict__ resO, short* __restrict__ fdist,
    const float* __restrict__ sArr, const float* __restrict__ attn_l,
    const float* __restrict__ attn_r, float* __restrict__ el, float* __restrict__ er) {
    __shared__ __align__(16) short Abuf[128 * 64];
    __shared__ __align__(16) short Bbuf[128 * 64];
    int b = blockIdx.x;
    const short *A, *W; short* C; const float* scale = nullptr;
    int N, do_elr = 0, rowBase, colBase;
    if (b < 2048) {
        A = feat_bf; W = fcw; C = feat_src; N = 512; do_elr = 1;
        colBase = (b & 3) * 128; rowBase = (b >> 2) * 128;
    } else if (b < 2560) {
        int bb = b - 2048;
        A = feat_bf; W = resw; C = resO; N = 512;
        colBase = (bb & 3) * 128; rowBase = (bb >> 2) * 128;
    } else {
        int bb = b - 2560;
        A = cf_bf; W = ww; C = fdist; scale = sArr; N = 128;
        colBase = 0; rowBase = bb * 128;
    }
    int t = threadIdx.x, wv = t >> 6, lane = t & 63;
    int l15 = lane & 15, quad = lane >> 4;
    const short* sbase = (wv < 2) ? (A + (size_t)rowBase * FIN)
                                  : (W + (size_t)colBase * FIN);
    short* dbase = (wv < 2) ? Abuf : Bbuf;
    int s0 = (wv & 1) * 8;
    int rsub = lane >> 3;
    int cg = (lane & 7) ^ rsub;

    f32x4 acc[2][8] = {};
    for (int kb = 0; kb < 4; kb++) {
#pragma unroll
        for (int q = 0; q < 8; q++) {
            int slab = s0 + q;
            int r_loc = slab * 8 + rsub;
            __builtin_amdgcn_global_load_lds(
                (const __attribute__((address_space(1))) void*)(sbase + (size_t)r_loc * FIN + kb * 64 + cg * 8),
                (__attribute__((address_space(3))) void*)(dbase + slab * 512), 16, 0, 0);
        }
        // Explicit drain of the async global->LDS DMA before the barrier.
        asm volatile("s_waitcnt vmcnt(0)" ::: "memory");
        __syncthreads();
#pragma unroll
        for (int kk = 0; kk < 2; kk++) {
            int gidx = (quad + kk * 4) ^ (l15 & 7);
            bf8 a[2], bfr[8];
#pragma unroll
            for (int i = 0; i < 2; i++) {
                int row = wv * 32 + i * 16 + l15;
                a[i] = *(const bf8*)(Abuf + (row * 8 + gidx) * 8);
            }
#pragma unroll
            for (int j = 0; j < 8; j++) {
                int row = j * 16 + l15;
                bfr[j] = *(const bf8*)(Bbuf + (row * 8 + gidx) * 8);
            }
#pragma unroll
            for (int i = 0; i < 2; i++)
#pragma unroll
                for (int j = 0; j < 8; j++)
                    acc[i][j] = __builtin_amdgcn_mfma_f32_16x16x32_bf16(a[i], bfr[j], acc[i][j], 0, 0, 0);
        }
        if (kb < 3) __syncthreads();
    }
#pragma unroll
    for (int i = 0; i < 2; i++)
#pragma unroll
        for (int r = 0; r < 4; r++) {
            int row = rowBase + wv * 32 + i * 16 + quad * 4 + r;
            float sc = scale ? scale[row] : 1.0f;
#pragma unroll
            for (int j = 0; j < 8; j++)
                C[(size_t)row * N + colBase + j * 16 + l15] = f2bf(acc[i][j][r] * sc);
        }
    if (do_elr) {
        int h = colBase >> 7;
        float alv[8], arv[8];
#pragma unroll
        for (int j = 0; j < 8; j++) {
            alv[j] = attn_l[h * HID + j * 16 + l15];
            arv[j] = attn_r[h * HID + j * 16 + l15];
        }
#pragma unroll
        for (int i = 0; i < 2; i++)
#pragma unroll
            for (int r = 0; r < 4; r++) {
                float dl = 0.f, dr = 0.f;
#pragma unroll
                for (int j = 0; j < 8; j++) {
                    float c = acc[i][j][r];
                    dl += c * alv[j];
                    dr += c * arv[j];
                }
                dl += __shfl_xor(dl, 1); dr += __shfl_xor(dr, 1);
                dl += __shfl_xor(dl, 2); dr += __shfl_xor(dr, 2);
                dl += __shfl_xor(dl, 4); dr += __shfl_xor(dr, 4);
                dl += __shfl_xor(dl, 8); dr += __shfl_xor(dr, 8);
                if (l15 == 0) {
                    int row = rowBase + wv * 32 + i * 16 + quad * 4 + r;
                    el[row * 4 + h] = dl;
                    if (row < N_DST) er[row * 4 + h] = dr;
                }
            }
    }
}

// ---- wave-per-dst softmax + aggregation + epilogue (no barriers) ----
__global__ __launch_bounds__(256) void k_agg(const int* __restrict__ offsets,
                                             const int* __restrict__ edge_ids,
                                             const int* __restrict__ src_idx,
                                             const float* __restrict__ el,
                                             const float* __restrict__ er,
                                             const short* __restrict__ feat_src,
                                             const short* __restrict__ res,
                                             const float* __restrict__ bias,
                                             const short* __restrict__ fdist,
                                             float* __restrict__ out) {
    int wv = threadIdx.x >> 6, lane = threadIdx.x & 63;
    int d = blockIdx.x * 4 + wv;
    int start = offsets[d];
    int cnt = offsets[d + 1] - start;
    float4 erv = *(const float4*)(er + (size_t)d * 4);
    float er0 = erv.x, er1 = erv.y, er2 = erv.z, er3 = erv.w;

    int srow0 = 0;
    float v0 = -1e30f, v1 = -1e30f, v2 = -1e30f, v3 = -1e30f;
    if (lane < cnt) {
        int e = edge_ids[start + lane];
        srow0 = src_idx[e];
        float4 lv = *(const float4*)(el + (size_t)srow0 * 4);
        v0 = lv.x + er0; v0 = v0 > 0 ? v0 : NEG * v0;
        v1 = lv.y + er1; v1 = v1 > 0 ? v1 : NEG * v1;
        v2 = lv.z + er2; v2 = v2 > 0 ? v2 : NEG * v2;
        v3 = lv.w + er3; v3 = v3 > 0 ? v3 : NEG * v3;
    }
    float m0 = v0, m1 = v1, m2 = v2, m3 = v3;
    for (int base = 64; base < cnt; base += 64) {
        if (base + lane < cnt) {
            int e = edge_ids[start + base + lane];
            int s = src_idx[e];
            float4 lv = *(const float4*)(el + (size_t)s * 4);
            float w0 = lv.x + er0; w0 = w0 > 0 ? w0 : NEG * w0; m0 = fmaxf(m0, w0);
            float w1 = lv.y + er1; w1 = w1 > 0 ? w1 : NEG * w1; m1 = fmaxf(m1, w1);
            float w2 = lv.z + er2; w2 = w2 > 0 ? w2 : NEG * w2; m2 = fmaxf(m2, w2);
            float w3 = lv.w + er3; w3 = w3 > 0 ? w3 : NEG * w3; m3 = fmaxf(m3, w3);
        }
    }
    for (int sh = 1; sh < 64; sh <<= 1) {
        m0 = fmaxf(m0, __shfl_xor(m0, sh)); m1 = fmaxf(m1, __shfl_xor(m1, sh));
        m2 = fmaxf(m2, __shfl_xor(m2, sh)); m3 = fmaxf(m3, __shfl_xor(m3, sh));
    }
    float s0 = 0.f, s1 = 0.f, s2 = 0.f, s3 = 0.f;
    if (lane < cnt) {
        s0 = __expf(v0 - m0); s1 = __expf(v1 - m1);
        s2 = __expf(v2 - m2); s3 = __expf(v3 - m3);
    }
    for (int base = 64; base < cnt; base += 64) {
        if (base + lane < cnt) {
            int e = edge_ids[start + base + lane];
            int s = src_idx[e];
            float4 lv = *(const float4*)(el + (size_t)s * 4);
            float w0 = lv.x + er0; w0 = w0 > 0 ? w0 : NEG * w0; s0 += __expf(w0 - m0);
            float w1 = lv.y + er1; w1 = w1 > 0 ? w1 : NEG * w1; s1 += __expf(w1 - m1);
            float w2 = lv.z + er2; w2 = w2 > 0 ? w2 : NEG * w2; s2 += __expf(w2 - m2);
            float w3 = lv.w + er3; w3 = w3 > 0 ? w3 : NEG * w3; s3 += __expf(w3 - m3);
        }
    }
    for (int sh = 1; sh < 64; sh <<= 1) {
        s0 += __shfl_xor(s0, sh); s1 += __shfl_xor(s1, sh);
        s2 += __shfl_xor(s2, sh); s3 += __shfl_xor(s3, sh);
    }
    float i0 = 1.f / fmaxf(s0, 1e-9f), i1 = 1.f / fmaxf(s1, 1e-9f);
    float i2 = 1.f / fmaxf(s2, 1e-9f), i3 = 1.f / fmaxf(s3, 1e-9f);

    float acc[8] = {0.f, 0.f, 0.f, 0.f, 0.f, 0.f, 0.f, 0.f};
    int c0 = lane * 8;
    int myh = lane >> 4;
    for (int base = 0; base < cnt; base += 64) {
        int nc = min(64, cnt - base);
        float a0, a1, a2, a3; int sr_;
        if (base == 0) {
            sr_ = srow0;
            a0 = __expf(v0 - m0) * i0; a1 = __expf(v1 - m1) * i1;
            a2 = __expf(v2 - m2) * i2; a3 = __expf(v3 - m3) * i3;
        } else {
            sr_ = 0; a0 = a1 = a2 = a3 = 0.f;
            if (base + lane < cnt) {
                int e = edge_ids[start + base + lane];
                sr_ = src_idx[e];
                float4 lv = *(const float4*)(el + (size_t)sr_ * 4);
                float w0 = lv.x + er0; w0 = w0 > 0 ? w0 : NEG * w0; a0 = __expf(w0 - m0) * i0;
                float w1 = lv.y + er1; w1 = w1 > 0 ? w1 : NEG * w1; a1 = __expf(w1 - m1) * i1;
                float w2 = lv.z + er2; w2 = w2 > 0 ? w2 : NEG * w2; a2 = __expf(w2 - m2) * i2;
                float w3 = lv.w + er3; w3 = w3 > 0 ? w3 : NEG * w3; a3 = __expf(w3 - m3) * i3;
            }
        }
        for (int c = 0; c < nc; c++) {
            int srw = __shfl(sr_, c);
            float b0 = __shfl(a0, c), b1 = __shfl(a1, c);
            float b2 = __shfl(a2, c), b3 = __shfl(a3, c);
            float af = myh == 0 ? b0 : (myh == 1 ? b1 : (myh == 2 ? b2 : b3));
            bf8 v = *(const bf8*)(feat_src + (size_t)srw * 512 + c0);
#pragma unroll
            for (int j = 0; j < 8; j++) acc[j] += af * bf2f(v[j]);
        }
    }

    bf8 rv = *(const bf8*)(res + (size_t)d * 512 + c0);
    float4 bv0 = *(const float4*)(bias + c0);
    float4 bv1 = *(const float4*)(bias + c0 + 4);
    float bb[8] = {bv0.x, bv0.y, bv0.z, bv0.w, bv1.x, bv1.y, bv1.z, bv1.w};
    bf8 fv = *(const bf8*)(fdist + (size_t)d * HID + (c0 & 127));
    float o[8];
#pragma unroll
    for (int j = 0; j < 8; j++) {
        float g = acc[j] + bf2f(rv[j]) + bb[j];
        g = g > 0 ? g : expm1f(g);
        float v = (g + bf2f(fv[j])) * 0.5f;
        o[j] = v > 0 ? v : 0.f;
    }
    float* op = out + (size_t)d * 512 + c0;
    *(float4*)op = make_float4(o[0], o[1], o[2], o[3]);
    *(float4*)(op + 4) = make_float4(o[4], o[5], o[6], o[7]);
}

extern "C" void kernel_launch(void* const* d_in, const int* in_sizes, int n_in,
                              void* d_out, int out_size, void* d_ws, size_t ws_size,
                              hipStream_t stream) {
    const float* feat      = (const float*)d_in[0];
    const float* poi_cat   = (const float*)d_in[1];
    const float* poi_coeff = (const float*)d_in[2];
    const float* fc_w      = (const float*)d_in[3];
    const float* attn_l    = (const float*)d_in[4];
    const float* attn_r    = (const float*)d_in[5];
    const float* bias_p    = (const float*)d_in[6];
    const float* res_w     = (const float*)d_in[7];
    const float* w_w       = (const float*)d_in[8];
    const int* src_idx     = (const int*)d_in[9];
    const int* dst_idx     = (const int*)d_in[10];
    const int* out_nodes   = (const int*)d_in[11];
    const int* ncounts     = (const int*)d_in[12];
    float* out = (float*)d_out;

    char* w = (char*)d_ws;
    auto alloc = [&](size_t bytes) -> char* {
        char* p = w; w += (bytes + 255) & ~(size_t)255; return p;
    };
    short* feat_bf  = (short*)alloc((size_t)N_SRC * FIN * 2);
    short* fcw_bf   = (short*)alloc((size_t)512 * FIN * 2);
    short* resw_bf  = (short*)alloc((size_t)512 * FIN * 2);
    short* ww_bf    = (short*)alloc((size_t)HID * FIN * 2);
    short* cf_bf    = (short*)alloc((size_t)N_DST * FIN * 2);
    short* feat_src = (short*)alloc((size_t)N_SRC * 512 * 2);
    short* res      = (short*)alloc((size_t)N_DST * 512 * 2);
    short* fdist    = (short*)alloc((size_t)N_DST * HID * 2);
    float* el       = (float*)alloc((size_t)N_SRC * 4 * 4);
    float* er       = (float*)alloc((size_t)N_DST * 4 * 4);
    float* sArr     = (float*)alloc((size_t)N_DST * 4);
    int* counts     = (int*)alloc((size_t)N_DST * 4);
    int* offsets    = (int*)alloc((size_t)(N_DST + 1) * 4);
    int* cursor     = (int*)alloc((size_t)N_DST * 4);
    int* edge_ids   = (int*)alloc((size_t)NEDGE * 4);

    hipMemsetAsync(counts, 0, N_DST * 4, stream);

    k_f2bf<<<N_SRC * FIN / 4 / 256, 256, 0, stream>>>(feat, feat_bf, N_SRC * FIN / 4);
    k_prep_w<<<288, 256, 0, stream>>>(fc_w, res_w, w_w, fcw_bf, resw_bf, ww_bf);
    k_prep_dst<<<N_DST / 4, 256, 0, stream>>>(poi_cat, poi_coeff, out_nodes, ncounts,
                                              cf_bf, sArr);

    k_hist<<<NEDGE / 256, 256, 0, stream>>>(dst_idx, counts);
    k_scan<<<1, 1024, 0, stream>>>(counts, offsets, cursor);
    k_scatter<<<NEDGE / 256, 256, 0, stream>>>(dst_idx, cursor, edge_ids);

    k_gemm_all<<<2688, 256, 0, stream>>>(feat_bf, fcw_bf, resw_bf, ww_bf, cf_bf,
                                         feat_src, res, fdist, sArr,
                                         attn_l, attn_r, el, er);

    k_agg<<<N_DST / 4, 256, 0, stream>>>(offsets, edge_ids, src_idx, el, er, feat_src,
                                         res, bias_p, fdist, out);
}